// Round 8
// baseline (581.233 us; speedup 1.0000x reference)
//
#include <hip/hip_runtime.h>
#include <hip/hip_fp16.h>
#include <math.h>

#define BATCH 16
#define CIN   12
#define HH    256
#define WW    256
#define HO    254
#define WO    254
#define PIX   (HO*WO)
#define COUT  16
#define CHW   (HH*WW)

typedef __attribute__((ext_vector_type(8))) _Float16 f16x8;
typedef __attribute__((ext_vector_type(4))) float f32x4;

__device__ __forceinline__ unsigned int f2h(float f) {
    return (unsigned int)__half_as_ushort(__float2half(f));
}
__device__ __forceinline__ unsigned long long pk4h(float a, float b, float c, float d) {
    unsigned int lo = f2h(a) | (f2h(b) << 16);
    unsigned int hi = f2h(c) | (f2h(d) << 16);
    return (unsigned long long)lo | ((unsigned long long)hi << 32);
}
__device__ __forceinline__ float hi_f(float v) { return (float)(_Float16)v; }
__device__ __forceinline__ int iclamp(int v, int lo, int hi) {
    return v < lo ? lo : (v > hi ? hi : v);
}

// Hybrid DCN:
//  - conv0 (offsets+mask) in EXACT fp32 scalar VALU: 4 threads/pixel (3 channels each),
//    wave-uniform weight indices (readfirstlane'd wave id) -> scalar K$ loads.
//  - dual einsum via R3-proven f16 MFMA skeleton with scaled hi/lo operands:
//    D = aH + aL/512, aH = sum Ah*Bh, aL = sum (Ah*Bl512 + Al512*Bh).
//    True error ~1e-6 (fp32 class). Two sequential passes (x1 then x2) reuse
//    one 32 KB LDS buffer pair; samples held in registers between passes.
// LDS: AB 32 KB (A-hi / A-lo*512, f16 [64][128] rows, 256B stride, linear) +
//      off_s 7 KB. Phase-0 overlays conv0 partials [4][64][28] in AB.
__global__ __launch_bounds__(256, 2) void dcn_hl(
    const float* __restrict__ x,
    const float* __restrict__ w0, const float* __restrict__ b0,
    const float* __restrict__ w1, const float* __restrict__ b1,
    const float* __restrict__ w2, const float* __restrict__ b2,
    const float* __restrict__ w3, const float* __restrict__ b3,
    float* __restrict__ out)
{
    __shared__ __align__(16) unsigned char AB[2*64*256];
    __shared__ float off_s[64][28];

    const int tid = threadIdx.x;
    const int p   = tid & 63;
    const int s   = __builtin_amdgcn_readfirstlane(tid >> 6);   // wave id, provably uniform
    const int l15 = p & 15;
    const int l4  = p >> 4;

    const int b   = blockIdx.z;
    const int ho  = blockIdx.y;
    const int wo0 = blockIdx.x * 64;
    const int wo  = min(wo0 + p, WO - 1);
    const float* xb = x + (size_t)b * (CIN*CHW);

    unsigned char* Ahb = AB;
    unsigned char* Alb = AB + 64*256;

    // ---- phase 0: conv0 partials over channels 3s..3s+2 (exact fp32) ----
    {
        float po[27];
        #pragma unroll
        for (int o = 0; o < 27; ++o) po[o] = 0.f;
        #pragma unroll
        for (int j = 0; j < 3; ++j) {
            const int c = 3*s + j;
            const float* xc = xb + (size_t)c*CHW + (size_t)ho*WW + wo;
            #pragma unroll
            for (int k = 0; k < 9; ++k) {
                const float v = xc[(k/3)*WW + (k%3)];
                #pragma unroll
                for (int o = 0; o < 18; ++o) po[o]    += v * w0[(o*CIN + c)*9 + k];
                #pragma unroll
                for (int o = 0; o < 9;  ++o) po[18+o] += v * w2[(o*CIN + c)*9 + k];
            }
        }
        float* part = (float*)AB;
        #pragma unroll
        for (int o = 0; o < 27; ++o) part[(s*64 + p)*28 + o] = po[o];
    }
    __syncthreads();

    // ---- reduce partials -> off_s (18 offsets + 9 sigmoid masks) ----
    {
        const float* part = (const float*)AB;
        #pragma unroll
        for (int j = 0; j < 7; ++j) {
            const int o = s*7 + j;
            if (o < 27) {
                float v = part[(0*64+p)*28 + o] + part[(1*64+p)*28 + o]
                        + part[(2*64+p)*28 + o] + part[(3*64+p)*28 + o];
                if (o < 18) v += b0[o];
                else        v = 1.f / (1.f + expf(-(v + b2[o-18])));
                off_s[p][o] = v;
            }
        }
    }
    __syncthreads();   // part dead; AB reusable as A-tiles

    // ---- sampling: build A1 (hi, lo*512); save masked samples in regs ----
    float vm[7][4];    // statically indexed (loop fully unrolled)
    {
        #pragma unroll
        for (int i = 0; i < 7; ++i) {
            const int u = s*7 + i;
            if (u < 27) {
                const int k = u/3, jq = u - k*3;
                const float dy = off_s[p][2*k], dx = off_s[p][2*k+1];
                const float mk = off_s[p][18 + k];
                const float py = dy + (float)(k/3) + (float)ho;
                const float px = dx + (float)(k%3) + (float)wo;
                const float y0f = floorf(py), x0f = floorf(px);
                const float fy = py - y0f, fx = px - x0f;
                const int y0 = (int)y0f, x0i = (int)x0f;
                const int y1 = y0 + 1,  x1i = x0i + 1;
                float w00 = (1.f-fy)*(1.f-fx);
                float w01 = (1.f-fy)*fx;
                float w10 = fy*(1.f-fx);
                float w11 = fy*fx;
                const bool vy0 = (unsigned)y0  < HH, vy1 = (unsigned)y1  < HH;
                const bool vx0 = (unsigned)x0i < WW, vx1 = (unsigned)x1i < WW;
                if (!(vy0 && vx0)) w00 = 0.f;
                if (!(vy0 && vx1)) w01 = 0.f;
                if (!(vy1 && vx0)) w10 = 0.f;
                if (!(vy1 && vx1)) w11 = 0.f;
                const int cy0 = iclamp(y0, 0, HH-1),  cy1 = iclamp(y1, 0, HH-1);
                const int cx0 = iclamp(x0i, 0, WW-1), cx1 = iclamp(x1i, 0, WW-1);
                const int i00 = cy0*WW + cx0, i01 = cy0*WW + cx1;
                const int i10 = cy1*WW + cx0, i11 = cy1*WW + cx1;

                float vv[4];
                #pragma unroll
                for (int c = 0; c < 4; ++c) {
                    const float* xc = xb + (size_t)(4*jq + c)*CHW;
                    vv[c] = w00*xc[i00] + w01*xc[i01] + w10*xc[i10] + w11*xc[i11];
                    vm[i][c] = vv[c] * mk;
                }
                const int boff = k*24 + 8*jq;
                *(unsigned long long*)(Ahb + p*256 + boff) =
                    pk4h(vv[0], vv[1], vv[2], vv[3]);
                *(unsigned long long*)(Alb + p*256 + boff) =
                    pk4h((vv[0]-hi_f(vv[0]))*512.f, (vv[1]-hi_f(vv[1]))*512.f,
                         (vv[2]-hi_f(vv[2]))*512.f, (vv[3]-hi_f(vv[3]))*512.f);
            }
        }
        // zero-pad K in [108,128): bytes 216..255 (persist through both passes)
        if (s < 3) {
            *(unsigned long long*)(Ahb + p*256 + 216 + 8*s) = 0ull;
            *(unsigned long long*)(Alb + p*256 + 216 + 8*s) = 0ull;
        } else {
            *(unsigned long long*)(Ahb + p*256 + 240) = 0ull;
            *(unsigned long long*)(Alb + p*256 + 240) = 0ull;
            *(unsigned long long*)(Ahb + p*256 + 248) = 0ull;
            *(unsigned long long*)(Alb + p*256 + 248) = 0ull;
        }
    }

    // ---- B-fragments pass 1 (w1): hi + lo*512, col o = l15 ----
    f16x8 beh[4], bel[4];
    #pragma unroll
    for (int kk = 0; kk < 4; ++kk) {
        f16x8 th, tl;
        #pragma unroll
        for (int ii = 0; ii < 8; ++ii) {
            const int K = kk*32 + (l4 << 3) + ii;
            float v = 0.f;
            if (K < 108) {
                const int tap = K/12, c = K%12;
                v = w1[(l15*CIN + c)*9 + tap];
            }
            th[ii] = (_Float16)v;
            tl[ii] = (_Float16)((v - hi_f(v)) * 512.f);
        }
        beh[kk] = th; bel[kk] = tl;
    }
    __syncthreads();   // A1 ready

    // ---- MFMA pass 1 (x1) + store ----
    {
        f32x4 aH = {0.f,0.f,0.f,0.f}, aL = {0.f,0.f,0.f,0.f};
        const int rowA = s*16 + l15;
        #pragma unroll
        for (int kk = 0; kk < 4; ++kk) {
            f16x8 ah = *(const f16x8*)(Ahb + rowA*256 + kk*64 + (l4 << 4));
            f16x8 al = *(const f16x8*)(Alb + rowA*256 + kk*64 + (l4 << 4));
            aH = __builtin_amdgcn_mfma_f32_16x16x32_f16(ah, beh[kk], aH, 0, 0, 0);
            aL = __builtin_amdgcn_mfma_f32_16x16x32_f16(ah, bel[kk], aL, 0, 0, 0);
            aL = __builtin_amdgcn_mfma_f32_16x16x32_f16(al, beh[kk], aL, 0, 0, 0);
        }
        const float bb = b1[l15];
        const int wob = wo0 + s*16 + (l4 << 2);
        float* dst = out + (size_t)(b*COUT + l15)*PIX + (size_t)ho*WO + wob;
        float r[4];
        #pragma unroll
        for (int e = 0; e < 4; ++e) r[e] = aH[e] + aL[e]*(1.f/512.f) + bb;
        if (wob + 4 <= WO) {
            float2 r01; r01.x = r[0]; r01.y = r[1];
            float2 r23; r23.x = r[2]; r23.y = r[3];
            *(float2*)(dst)     = r01;
            *(float2*)(dst + 2) = r23;
        } else {
            #pragma unroll
            for (int e = 0; e < 4; ++e)
                if (wob + e < WO) dst[e] = r[e];
        }
    }
    __syncthreads();   // pass-1 reads done; buffers reusable

    // ---- build A2 (masked samples) from registers ----
    {
        #pragma unroll
        for (int i = 0; i < 7; ++i) {
            const int u = s*7 + i;
            if (u < 27) {
                const int k = u/3, jq = u - k*3;
                const int boff = k*24 + 8*jq;
                *(unsigned long long*)(Ahb + p*256 + boff) =
                    pk4h(vm[i][0], vm[i][1], vm[i][2], vm[i][3]);
                *(unsigned long long*)(Alb + p*256 + boff) =
                    pk4h((vm[i][0]-hi_f(vm[i][0]))*512.f, (vm[i][1]-hi_f(vm[i][1]))*512.f,
                         (vm[i][2]-hi_f(vm[i][2]))*512.f, (vm[i][3]-hi_f(vm[i][3]))*512.f);
            }
        }
        // pads untouched -> still zero
    }

    // ---- B-fragments pass 2 (w3) ----
    #pragma unroll
    for (int kk = 0; kk < 4; ++kk) {
        f16x8 th, tl;
        #pragma unroll
        for (int ii = 0; ii < 8; ++ii) {
            const int K = kk*32 + (l4 << 3) + ii;
            float v = 0.f;
            if (K < 108) {
                const int tap = K/12, c = K%12;
                v = w3[(l15*CIN + c)*9 + tap];
            }
            th[ii] = (_Float16)v;
            tl[ii] = (_Float16)((v - hi_f(v)) * 512.f);
        }
        beh[kk] = th; bel[kk] = tl;
    }
    __syncthreads();   // A2 ready

    // ---- MFMA pass 2 (x2) + store ----
    {
        f32x4 aH = {0.f,0.f,0.f,0.f}, aL = {0.f,0.f,0.f,0.f};
        const int rowA = s*16 + l15;
        #pragma unroll
        for (int kk = 0; kk < 4; ++kk) {
            f16x8 ah = *(const f16x8*)(Ahb + rowA*256 + kk*64 + (l4 << 4));
            f16x8 al = *(const f16x8*)(Alb + rowA*256 + kk*64 + (l4 << 4));
            aH = __builtin_amdgcn_mfma_f32_16x16x32_f16(ah, beh[kk], aH, 0, 0, 0);
            aL = __builtin_amdgcn_mfma_f32_16x16x32_f16(ah, bel[kk], aL, 0, 0, 0);
            aL = __builtin_amdgcn_mfma_f32_16x16x32_f16(al, beh[kk], aL, 0, 0, 0);
        }
        const float bb = b3[l15];
        const int wob = wo0 + s*16 + (l4 << 2);
        float* dst = out + (size_t)(BATCH*COUT)*PIX
                         + (size_t)(b*COUT + l15)*PIX + (size_t)ho*WO + wob;
        float r[4];
        #pragma unroll
        for (int e = 0; e < 4; ++e) r[e] = aH[e] + aL[e]*(1.f/512.f) + bb;
        if (wob + 4 <= WO) {
            float2 r01; r01.x = r[0]; r01.y = r[1];
            float2 r23; r23.x = r[2]; r23.y = r[3];
            *(float2*)(dst)     = r01;
            *(float2*)(dst + 2) = r23;
        } else {
            #pragma unroll
            for (int e = 0; e < 4; ++e)
                if (wob + e < WO) dst[e] = r[e];
        }
    }
}

extern "C" void kernel_launch(void* const* d_in, const int* in_sizes, int n_in,
                              void* d_out, int out_size, void* d_ws, size_t ws_size,
                              hipStream_t stream) {
    const float* x  = (const float*)d_in[0];
    const float* w0 = (const float*)d_in[1];
    const float* b0 = (const float*)d_in[2];
    const float* w1 = (const float*)d_in[3];
    const float* b1 = (const float*)d_in[4];
    const float* w2 = (const float*)d_in[5];
    const float* b2 = (const float*)d_in[6];
    const float* w3 = (const float*)d_in[7];
    const float* b3 = (const float*)d_in[8];
    float* out = (float*)d_out;

    dim3 block(256);
    dim3 grid(4, HO, BATCH);   // 4 x 64-pixel row segments, 254 rows, 16 batches
    dcn_hl<<<grid, block, 0, stream>>>(x, w0, b0, w1, b1, w2, b2, w3, b3, out);
}

// Round 9
// 516.877 us; speedup vs baseline: 1.1245x; 1.1245x over previous
//
#include <hip/hip_runtime.h>
#include <hip/hip_fp16.h>
#include <math.h>

#define BATCH 16
#define CIN   12
#define HH    256
#define WW    256
#define HO    254
#define WO    254
#define PIX   (HO*WO)
#define COUT  16
#define CHW   (HH*WW)

typedef __attribute__((ext_vector_type(8))) _Float16 f16x8;
typedef __attribute__((ext_vector_type(4))) float f32x4;

__device__ __forceinline__ unsigned int f2h(float f) {
    return (unsigned int)__half_as_ushort(__float2half(f));
}
__device__ __forceinline__ unsigned long long pk4h(float a, float b, float c, float d) {
    unsigned int lo = f2h(a) | (f2h(b) << 16);
    unsigned int hi = f2h(c) | (f2h(d) << 16);
    return (unsigned long long)lo | ((unsigned long long)hi << 32);
}
__device__ __forceinline__ float hi_f(float v) { return (float)(_Float16)v; }
__device__ __forceinline__ int iclamp(int v, int lo, int hi) {
    return v < lo ? lo : (v > hi ? hi : v);
}

// XOR swizzle: permutes 16B slots within a 256B row by row&15.
// Write side (8B units, bit 3 preserved) and read side (16B b128 reads)
// apply the SAME function -> bijective, numerics untouched.
#define SWZ(r, off) ((off) ^ (((r) & 15) << 4))

// R8 structure (green) + bank-conflict fixes + 4 blocks/CU:
//  - conv0 exact fp32, 4 threads/pixel, partials stride 29 (conflict-free)
//  - off_s stride 29 (conflict-free)
//  - A-tiles XOR-swizzled: reads min-cycle, writes ~2-way (free)
__global__ __launch_bounds__(256, 4) void dcn_hl(
    const float* __restrict__ x,
    const float* __restrict__ w0, const float* __restrict__ b0,
    const float* __restrict__ w1, const float* __restrict__ b1,
    const float* __restrict__ w2, const float* __restrict__ b2,
    const float* __restrict__ w3, const float* __restrict__ b3,
    float* __restrict__ out)
{
    __shared__ __align__(16) unsigned char AB[2*64*256];   // Ahb/Alb; phase-0 overlays partials
    __shared__ float off_s[64][29];                        // 18 offsets + 9 sigmoid masks

    const int tid = threadIdx.x;
    const int p   = tid & 63;
    const int s   = __builtin_amdgcn_readfirstlane(tid >> 6);   // wave id, uniform
    const int l15 = p & 15;
    const int l4  = p >> 4;

    const int b   = blockIdx.z;
    const int ho  = blockIdx.y;
    const int wo0 = blockIdx.x * 64;
    const int wo  = min(wo0 + p, WO - 1);
    const float* xb = x + (size_t)b * (CIN*CHW);

    unsigned char* Ahb = AB;
    unsigned char* Alb = AB + 64*256;

    // ---- phase 0: conv0 partials over channels 3s..3s+2 (exact fp32) ----
    {
        float po[27];
        #pragma unroll
        for (int o = 0; o < 27; ++o) po[o] = 0.f;
        #pragma unroll
        for (int j = 0; j < 3; ++j) {
            const int c = 3*s + j;
            const float* xc = xb + (size_t)c*CHW + (size_t)ho*WW + wo;
            #pragma unroll
            for (int k = 0; k < 9; ++k) {
                const float v = xc[(k/3)*WW + (k%3)];
                #pragma unroll
                for (int o = 0; o < 18; ++o) po[o]    += v * w0[(o*CIN + c)*9 + k];
                #pragma unroll
                for (int o = 0; o < 9;  ++o) po[18+o] += v * w2[(o*CIN + c)*9 + k];
            }
        }
        float* part = (float*)AB;
        #pragma unroll
        for (int o = 0; o < 27; ++o) part[(s*64 + p)*29 + o] = po[o];   // stride 29: conflict-free
    }
    __syncthreads();

    // ---- reduce partials -> off_s (18 offsets + 9 sigmoid masks) ----
    {
        const float* part = (const float*)AB;
        #pragma unroll
        for (int j = 0; j < 7; ++j) {
            const int o = s*7 + j;
            if (o < 27) {
                float v = part[(0*64+p)*29 + o] + part[(1*64+p)*29 + o]
                        + part[(2*64+p)*29 + o] + part[(3*64+p)*29 + o];
                if (o < 18) v += b0[o];
                else        v = 1.f / (1.f + expf(-(v + b2[o-18])));
                off_s[p][o] = v;
            }
        }
    }
    __syncthreads();   // partials dead; AB reusable as A-tiles

    // ---- sampling: build A1 (hi, lo*512) swizzled; save masked samples in regs ----
    float vm[7][4];    // statically indexed (fully unrolled)
    {
        #pragma unroll
        for (int i = 0; i < 7; ++i) {
            const int u = s*7 + i;
            if (u < 27) {
                const int k = u/3, jq = u - k*3;
                const float dy = off_s[p][2*k], dx = off_s[p][2*k+1];
                const float mk = off_s[p][18 + k];
                const float py = dy + (float)(k/3) + (float)ho;
                const float px = dx + (float)(k%3) + (float)wo;
                const float y0f = floorf(py), x0f = floorf(px);
                const float fy = py - y0f, fx = px - x0f;
                const int y0 = (int)y0f, x0i = (int)x0f;
                const int y1 = y0 + 1,  x1i = x0i + 1;
                float w00 = (1.f-fy)*(1.f-fx);
                float w01 = (1.f-fy)*fx;
                float w10 = fy*(1.f-fx);
                float w11 = fy*fx;
                const bool vy0 = (unsigned)y0  < HH, vy1 = (unsigned)y1  < HH;
                const bool vx0 = (unsigned)x0i < WW, vx1 = (unsigned)x1i < WW;
                if (!(vy0 && vx0)) w00 = 0.f;
                if (!(vy0 && vx1)) w01 = 0.f;
                if (!(vy1 && vx0)) w10 = 0.f;
                if (!(vy1 && vx1)) w11 = 0.f;
                const int cy0 = iclamp(y0, 0, HH-1),  cy1 = iclamp(y1, 0, HH-1);
                const int cx0 = iclamp(x0i, 0, WW-1), cx1 = iclamp(x1i, 0, WW-1);
                const int i00 = cy0*WW + cx0, i01 = cy0*WW + cx1;
                const int i10 = cy1*WW + cx0, i11 = cy1*WW + cx1;

                float vv[4];
                #pragma unroll
                for (int c = 0; c < 4; ++c) {
                    const float* xc = xb + (size_t)(4*jq + c)*CHW;
                    vv[c] = w00*xc[i00] + w01*xc[i01] + w10*xc[i10] + w11*xc[i11];
                    vm[i][c] = vv[c] * mk;
                }
                const int boff = SWZ(p, k*24 + 8*jq);
                *(unsigned long long*)(Ahb + p*256 + boff) =
                    pk4h(vv[0], vv[1], vv[2], vv[3]);
                *(unsigned long long*)(Alb + p*256 + boff) =
                    pk4h((vv[0]-hi_f(vv[0]))*512.f, (vv[1]-hi_f(vv[1]))*512.f,
                         (vv[2]-hi_f(vv[2]))*512.f, (vv[3]-hi_f(vv[3]))*512.f);
            }
        }
        // zero-pad K in [108,128): bytes 216..255 (swizzled; persist both passes)
        if (s < 3) {
            const int boff = SWZ(p, 216 + 8*s);
            *(unsigned long long*)(Ahb + p*256 + boff) = 0ull;
            *(unsigned long long*)(Alb + p*256 + boff) = 0ull;
        } else {
            const int b0f = SWZ(p, 240), b1f = SWZ(p, 248);
            *(unsigned long long*)(Ahb + p*256 + b0f) = 0ull;
            *(unsigned long long*)(Alb + p*256 + b0f) = 0ull;
            *(unsigned long long*)(Ahb + p*256 + b1f) = 0ull;
            *(unsigned long long*)(Alb + p*256 + b1f) = 0ull;
        }
    }

    // ---- B-fragments pass 1 (w1): hi + lo*512, col o = l15 ----
    f16x8 beh[4], bel[4];
    #pragma unroll
    for (int kk = 0; kk < 4; ++kk) {
        f16x8 th, tl;
        #pragma unroll
        for (int ii = 0; ii < 8; ++ii) {
            const int K = kk*32 + (l4 << 3) + ii;
            float v = 0.f;
            if (K < 108) {
                const int tap = K/12, c = K%12;
                v = w1[(l15*CIN + c)*9 + tap];
            }
            th[ii] = (_Float16)v;
            tl[ii] = (_Float16)((v - hi_f(v)) * 512.f);
        }
        beh[kk] = th; bel[kk] = tl;
    }
    __syncthreads();   // A1 ready

    // ---- MFMA pass 1 (x1) + store ----
    {
        f32x4 aH = {0.f,0.f,0.f,0.f}, aL = {0.f,0.f,0.f,0.f};
        const int rowA = s*16 + l15;
        #pragma unroll
        for (int kk = 0; kk < 4; ++kk) {
            const int roff = SWZ(rowA, kk*64 + (l4 << 4));
            f16x8 ah = *(const f16x8*)(Ahb + rowA*256 + roff);
            f16x8 al = *(const f16x8*)(Alb + rowA*256 + roff);
            aH = __builtin_amdgcn_mfma_f32_16x16x32_f16(ah, beh[kk], aH, 0, 0, 0);
            aL = __builtin_amdgcn_mfma_f32_16x16x32_f16(ah, bel[kk], aL, 0, 0, 0);
            aL = __builtin_amdgcn_mfma_f32_16x16x32_f16(al, beh[kk], aL, 0, 0, 0);
        }
        const float bb = b1[l15];
        const int wob = wo0 + s*16 + (l4 << 2);
        float* dst = out + (size_t)(b*COUT + l15)*PIX + (size_t)ho*WO + wob;
        float r[4];
        #pragma unroll
        for (int e = 0; e < 4; ++e) r[e] = aH[e] + aL[e]*(1.f/512.f) + bb;
        if (wob + 4 <= WO) {
            float2 r01; r01.x = r[0]; r01.y = r[1];
            float2 r23; r23.x = r[2]; r23.y = r[3];
            *(float2*)(dst)     = r01;
            *(float2*)(dst + 2) = r23;
        } else {
            #pragma unroll
            for (int e = 0; e < 4; ++e)
                if (wob + e < WO) dst[e] = r[e];
        }
    }
    __syncthreads();   // pass-1 reads done; buffers reusable

    // ---- build A2 (masked samples) from registers, swizzled ----
    {
        #pragma unroll
        for (int i = 0; i < 7; ++i) {
            const int u = s*7 + i;
            if (u < 27) {
                const int k = u/3, jq = u - k*3;
                const int boff = SWZ(p, k*24 + 8*jq);
                *(unsigned long long*)(Ahb + p*256 + boff) =
                    pk4h(vm[i][0], vm[i][1], vm[i][2], vm[i][3]);
                *(unsigned long long*)(Alb + p*256 + boff) =
                    pk4h((vm[i][0]-hi_f(vm[i][0]))*512.f, (vm[i][1]-hi_f(vm[i][1]))*512.f,
                         (vm[i][2]-hi_f(vm[i][2]))*512.f, (vm[i][3]-hi_f(vm[i][3]))*512.f);
            }
        }
        // pads untouched -> still zero
    }

    // ---- B-fragments pass 2 (w3) ----
    #pragma unroll
    for (int kk = 0; kk < 4; ++kk) {
        f16x8 th, tl;
        #pragma unroll
        for (int ii = 0; ii < 8; ++ii) {
            const int K = kk*32 + (l4 << 3) + ii;
            float v = 0.f;
            if (K < 108) {
                const int tap = K/12, c = K%12;
                v = w3[(l15*CIN + c)*9 + tap];
            }
            th[ii] = (_Float16)v;
            tl[ii] = (_Float16)((v - hi_f(v)) * 512.f);
        }
        beh[kk] = th; bel[kk] = tl;
    }
    __syncthreads();   // A2 ready

    // ---- MFMA pass 2 (x2) + store ----
    {
        f32x4 aH = {0.f,0.f,0.f,0.f}, aL = {0.f,0.f,0.f,0.f};
        const int rowA = s*16 + l15;
        #pragma unroll
        for (int kk = 0; kk < 4; ++kk) {
            const int roff = SWZ(rowA, kk*64 + (l4 << 4));
            f16x8 ah = *(const f16x8*)(Ahb + rowA*256 + roff);
            f16x8 al = *(const f16x8*)(Alb + rowA*256 + roff);
            aH = __builtin_amdgcn_mfma_f32_16x16x32_f16(ah, beh[kk], aH, 0, 0, 0);
            aL = __builtin_amdgcn_mfma_f32_16x16x32_f16(ah, bel[kk], aL, 0, 0, 0);
            aL = __builtin_amdgcn_mfma_f32_16x16x32_f16(al, beh[kk], aL, 0, 0, 0);
        }
        const float bb = b3[l15];
        const int wob = wo0 + s*16 + (l4 << 2);
        float* dst = out + (size_t)(BATCH*COUT)*PIX
                         + (size_t)(b*COUT + l15)*PIX + (size_t)ho*WO + wob;
        float r[4];
        #pragma unroll
        for (int e = 0; e < 4; ++e) r[e] = aH[e] + aL[e]*(1.f/512.f) + bb;
        if (wob + 4 <= WO) {
            float2 r01; r01.x = r[0]; r01.y = r[1];
            float2 r23; r23.x = r[2]; r23.y = r[3];
            *(float2*)(dst)     = r01;
            *(float2*)(dst + 2) = r23;
        } else {
            #pragma unroll
            for (int e = 0; e < 4; ++e)
                if (wob + e < WO) dst[e] = r[e];
        }
    }
}

extern "C" void kernel_launch(void* const* d_in, const int* in_sizes, int n_in,
                              void* d_out, int out_size, void* d_ws, size_t ws_size,
                              hipStream_t stream) {
    const float* x  = (const float*)d_in[0];
    const float* w0 = (const float*)d_in[1];
    const float* b0 = (const float*)d_in[2];
    const float* w1 = (const float*)d_in[3];
    const float* b1 = (const float*)d_in[4];
    const float* w2 = (const float*)d_in[5];
    const float* b2 = (const float*)d_in[6];
    const float* w3 = (const float*)d_in[7];
    const float* b3 = (const float*)d_in[8];
    float* out = (float*)d_out;

    dim3 block(256);
    dim3 grid(4, HO, BATCH);   // 4 x 64-pixel row segments, 254 rows, 16 batches
    dcn_hl<<<grid, block, 0, stream>>>(x, w0, b0, w1, b1, w2, b2, w3, b3, out);
}